// Round 13
// baseline (152.379 us; speedup 1.0000x reference)
//
#include <hip/hip_runtime.h>

#define H_SIZE 1024
#define N_HEADS 16
#define D_K 64
#define SEQ 2048
#define BATCH 2
#define M_TOT 4096  // BATCH*SEQ

typedef __bf16 __attribute__((ext_vector_type(8))) bf16_8;
typedef float __attribute__((ext_vector_type(4))) f32x4;
typedef float __attribute__((ext_vector_type(16))) f32x16;
typedef int __attribute__((ext_vector_type(4))) int4v;

// row-swizzle for 128B-row LDS tiles (attn): spread rows sharing (r&7) across segments
#define SWZ(r) ((((r) & 7) ^ (((r) >> 3) & 7)))

__device__ __forceinline__ ushort f2bf(float f) {
    unsigned int u = __float_as_uint(f);
    unsigned int r = (u + 0x7FFFu + ((u >> 16) & 1u)) >> 16;
    return (ushort)r;
}

__device__ __forceinline__ unsigned int cvtpk(float lo, float hi) {
    unsigned int r;
    asm("v_cvt_pk_bf16_f32 %0, %1, %2" : "=v"(r) : "v"(lo), "v"(hi));
    return r;
}

__device__ __forceinline__ float exp2_raw(float x) {
    float r;
    asm("v_exp_f32 %0, %1" : "=v"(r) : "v"(x));
    return r;
}

__device__ __forceinline__ void gld16(void* lds, const void* g) {
    __builtin_amdgcn_global_load_lds(
        (const __attribute__((address_space(1))) unsigned int*)g,
        (__attribute__((address_space(3))) unsigned int*)lds, 16, 0, 0);
}

// ---------------- fused cast fp32 -> bf16 for x + 4 weight matrices ----------------
__global__ __launch_bounds__(256) void cast_all_kernel(
    const float* __restrict__ x, const float* __restrict__ wq, const float* __restrict__ wk,
    const float* __restrict__ wv, const float* __restrict__ wo,
    ushort* __restrict__ xb, ushort* __restrict__ wqb, ushort* __restrict__ wkb,
    ushort* __restrict__ wvb, ushort* __restrict__ wob) {
    int i = blockIdx.x * 256 + threadIdx.x;  // float4 index
    const float* src;
    ushort* dst;
    int off;
    if (i < 1048576) {          // x: 4096*1024/4
        src = x; dst = xb; off = i;
    } else {
        int j = i - 1048576;    // each W: 1024*1024/4 = 262144
        int w = j >> 18;
        off = j & 262143;
        src = (w == 0) ? wq : (w == 1) ? wk : (w == 2) ? wv : wo;
        dst = (w == 0) ? wqb : (w == 1) ? wkb : (w == 2) ? wvb : wob;
    }
    float4 v = ((const float4*)src)[off];
    ushort4 o;
    o.x = f2bf(v.x); o.y = f2bf(v.y); o.z = f2bf(v.z); o.w = f2bf(v.w);
    ((ushort4*)dst)[off] = o;
}

// ---------------- fused QKV GEMM: triple-buffered BK=32, counted vmcnt, gld16 ----------------
// Natural block order (r8 config): best measured A/W reuse split across XCDs.
__global__ __launch_bounds__(256) void gemm_qkv(
    const ushort* __restrict__ A, const ushort* __restrict__ wq,
    const ushort* __restrict__ wk, const ushort* __restrict__ wv,
    const float* __restrict__ bq, const float* __restrict__ bk, const float* __restrict__ bv,
    ushort* __restrict__ Qb, ushort* __restrict__ Kb, ushort* __restrict__ Vtb) {
    constexpr int BK = 32;
    __shared__ ushort As[3][128 * BK];   // 24 KB
    __shared__ ushort Bs[3][128 * BK];   // 24 KB
    const int tid = threadIdx.x;
    const int lane = tid & 63, wid = tid >> 6;
    const int wr = wid >> 1, wc = wid & 1;
    const int hi = lane >> 4, lo = lane & 15;
    const int bm0 = blockIdx.x * 128;
    const int t3 = blockIdx.y >> 3;
    const int bn0 = (blockIdx.y & 7) * 128;
    const ushort* Bw = (t3 == 0) ? wq : (t3 == 1) ? wk : wv;
    const float* bias = (t3 == 0) ? bq : (t3 == 1) ? bk : bv;

    f32x4 acc[4][4] = {};

    const int srow = tid >> 2;
    const int sseg = ((tid & 3) ^ ((tid >> 3) & 3)) * 8;  // ushort offset
    const ushort* gaB = A + (size_t)(bm0 + srow) * H_SIZE + sseg;
    const ushort* gbB = Bw + (size_t)(bn0 + srow) * H_SIZE + sseg;
    const int ldsOff = tid * 16;  // bytes

#define STAGE(ba, bb, kt)                                 \
    {                                                     \
        char* la = (char*)(ba) + ldsOff;                  \
        char* lb = (char*)(bb) + ldsOff;                  \
        gld16(la, gaB + (kt));                            \
        gld16(la + 4096, gaB + 64 * H_SIZE + (kt));       \
        gld16(lb, gbB + (kt));                            \
        gld16(lb + 4096, gbB + 64 * H_SIZE + (kt));       \
    }

    STAGE(&As[0][0], &Bs[0][0], 0);
    STAGE(&As[1][0], &Bs[1][0], BK);
    asm volatile("s_waitcnt vmcnt(4)" ::: "memory");
    __builtin_amdgcn_s_barrier();
    __builtin_amdgcn_sched_barrier(0);

    constexpr int NT = H_SIZE / BK;  // 32
    const int rxv = (lo >> 1) & 3;   // read-side swizzle term
    int cur = 0;
    for (int t = 0; t < NT; t++) {
        int c2 = cur + 2; if (c2 >= 3) c2 -= 3;
        if (t + 2 < NT) STAGE(&As[c2][0], &Bs[c2][0], (t + 2) * BK);
        {
            bf16_8 af[4], bfv[4];
            const ushort* pa = &As[cur][(wr * 64 + lo) * BK + ((hi ^ rxv) * 8)];
            const ushort* pb = &Bs[cur][(wc * 64 + lo) * BK + ((hi ^ rxv) * 8)];
#pragma unroll
            for (int i = 0; i < 4; i++) af[i] = *(const bf16_8*)(pa + i * 16 * BK);
#pragma unroll
            for (int i = 0; i < 4; i++) bfv[i] = *(const bf16_8*)(pb + i * 16 * BK);
#pragma unroll
            for (int mi = 0; mi < 4; mi++)
#pragma unroll
                for (int ni = 0; ni < 4; ni++)
                    acc[mi][ni] = __builtin_amdgcn_mfma_f32_16x16x32_bf16(
                        af[mi], bfv[ni], acc[mi][ni], 0, 0, 0);
        }
        if (t + 1 < NT) {
            if (t + 2 < NT) { asm volatile("s_waitcnt vmcnt(4)" ::: "memory"); }
            else            { asm volatile("s_waitcnt vmcnt(0)" ::: "memory"); }
            __builtin_amdgcn_s_barrier();
            __builtin_amdgcn_sched_barrier(0);
        }
        cur = cur + 1; if (cur >= 3) cur -= 3;
    }
#undef STAGE

#pragma unroll
    for (int mi = 0; mi < 4; mi++) {
#pragma unroll
        for (int ni = 0; ni < 4; ni++) {
            const int row0 = bm0 + wr * 64 + mi * 16 + hi * 4;
            const int col = bn0 + wc * 64 + ni * 16 + lo;
            const float bv = bias[col];
            const int h = col >> 6, dk = col & 63;
            if (t3 == 2) {
                const int b = row0 >> 11, l0 = row0 & 2047;
                const int lsw0 = (l0 & ~63) | (((((l0 >> 3) & 7) ^ SWZ(dk)) & 7) << 3) | (l0 & 7);
                uint2 o;
                o.x = cvtpk(acc[mi][ni][0] + bv, acc[mi][ni][1] + bv);
                o.y = cvtpk(acc[mi][ni][2] + bv, acc[mi][ni][3] + bv);
                *(uint2*)&Vtb[((size_t)(b * N_HEADS + h) * D_K + dk) * SEQ + lsw0] = o;
            } else {
#pragma unroll
                for (int rr = 0; rr < 4; rr++) {
                    const int m = row0 + rr;
                    const int b = m >> 11, l = m & 2047;
                    float val = acc[mi][ni][rr] + bv;
                    if (t3 == 0) {
                        Qb[((size_t)(b * N_HEADS + h) * SEQ + l) * D_K + dk] =
                            f2bf(val * 0.18033688f);
                    } else {
                        int dks = ((((dk >> 3) ^ SWZ(l & 63)) & 7) << 3) | (dk & 7);
                        Kb[((size_t)(b * N_HEADS + h) * SEQ + l) * D_K + dks] = f2bf(val);
                    }
                }
            }
        }
    }
}

// ---------------- O-projection GEMM 128x64 with FUSED split-K combine ----------------
// A-tile = (Op0 + Op1) * 1/(l0+l1), computed in-register during staging (2-buf, 1 barrier/iter).
// B-side stays gld16-direct. Deletes the standalone combine kernel + Ao round-trip.
__global__ __launch_bounds__(256) void gemm_o(const ushort* __restrict__ Op0,
                                              const ushort* __restrict__ Op1,
                                              const float* __restrict__ Lp,
                                              const ushort* __restrict__ Bw,
                                              const float* __restrict__ bias,
                                              const float* __restrict__ resid,
                                              float* __restrict__ outp) {
    constexpr int BK = 32;
    __shared__ ushort As[2][128 * BK];  // 16 KB
    __shared__ ushort Bs[2][64 * BK];   // 8 KB
    const int tid = threadIdx.x;
    const int lane = tid & 63, wid = tid >> 6;
    const int wr = wid >> 1, wc = wid & 1;
    const int hi = lane >> 4, lo = lane & 15;
    const int bm0 = blockIdx.x * 128, bn0 = blockIdx.y * 64;

    f32x4 acc[4][2] = {};

    const int srow = tid >> 2;         // 0..63 (A rows srow, srow+64; B row srow)
    const int c4 = tid & 3;            // 8-ushort chunk within 32-wide K tile
    const int pseg = (c4 ^ ((srow >> 1) & 3)) * 8;   // physical LDS seg (ushorts)
    const int m0 = bm0 + srow, m1 = bm0 + srow + 64;
    const int b0 = m0 >> 11, l0r = m0 & 2047;
    const int b1 = m1 >> 11, l1r = m1 & 2047;
    const ushort* gbB = Bw + (size_t)(bn0 + srow) * H_SIZE + pseg;

    uint4 a0, a1, a2, a3;
    float lp00, lp01, lp10, lp11;

#define LOAD_AB(t1)                                                               \
    {                                                                             \
        gld16((char*)&Bs[(t1) & 1][0] + tid * 16, gbB + (t1) * BK);               \
        const int colb = (t1) * BK + c4 * 8;                                      \
        a0 = *(const uint4*)(Op0 + (size_t)m0 * H_SIZE + colb);                   \
        a1 = *(const uint4*)(Op1 + (size_t)m0 * H_SIZE + colb);                   \
        a2 = *(const uint4*)(Op0 + (size_t)m1 * H_SIZE + colb);                   \
        a3 = *(const uint4*)(Op1 + (size_t)m1 * H_SIZE + colb);                   \
        const int h = (t1) >> 1;                                                  \
        lp00 = Lp[(size_t)(b0 * N_HEADS + h) * SEQ + l0r];                        \
        lp01 = Lp[65536 + (size_t)(b0 * N_HEADS + h) * SEQ + l0r];                \
        lp10 = Lp[(size_t)(b1 * N_HEADS + h) * SEQ + l1r];                        \
        lp11 = Lp[65536 + (size_t)(b1 * N_HEADS + h) * SEQ + l1r];                \
    }

#define COMBINE_WRITE(t1)                                                         \
    {                                                                             \
        const float inv0 = 1.0f / (lp00 + lp01);                                  \
        const float inv1 = 1.0f / (lp10 + lp11);                                  \
        unsigned int w0[4], w1[4];                                                \
        const unsigned int* pa = (const unsigned int*)&a0;                        \
        const unsigned int* pc = (const unsigned int*)&a1;                        \
        const unsigned int* pd = (const unsigned int*)&a2;                        \
        const unsigned int* pe = (const unsigned int*)&a3;                        \
        _Pragma("unroll")                                                         \
        for (int j = 0; j < 4; j++) {                                             \
            float vlo = __uint_as_float(pa[j] << 16) + __uint_as_float(pc[j] << 16); \
            float vhi = __uint_as_float(pa[j] & 0xFFFF0000u) +                    \
                        __uint_as_float(pc[j] & 0xFFFF0000u);                     \
            w0[j] = cvtpk(vlo * inv0, vhi * inv0);                                \
            float ulo = __uint_as_float(pd[j] << 16) + __uint_as_float(pe[j] << 16); \
            float uhi = __uint_as_float(pd[j] & 0xFFFF0000u) +                    \
                        __uint_as_float(pe[j] & 0xFFFF0000u);                     \
            w1[j] = cvtpk(ulo * inv1, uhi * inv1);                                \
        }                                                                         \
        ushort* dst = &As[(t1) & 1][srow * BK + pseg];                            \
        *(uint4*)dst = *(const uint4*)w0;                                         \
        *(uint4*)(dst + 64 * BK) = *(const uint4*)w1;                             \
    }

    // prologue: stage tile 0
    LOAD_AB(0);
    asm volatile("s_waitcnt vmcnt(0)" ::: "memory");
    COMBINE_WRITE(0);
    __syncthreads();

    constexpr int NT = H_SIZE / BK;
    const int rxv = (lo >> 1) & 3;
    for (int t = 0; t < NT; t++) {
        const int cur = t & 1;
        if (t + 1 < NT) LOAD_AB(t + 1);
        {
            bf16_8 af[4], bfv[2];
            const ushort* pa = &As[cur][(wr * 64 + lo) * BK + ((hi ^ rxv) * 8)];
            const ushort* pb = &Bs[cur][(wc * 32 + lo) * BK + ((hi ^ rxv) * 8)];
#pragma unroll
            for (int i = 0; i < 4; i++) af[i] = *(const bf16_8*)(pa + i * 16 * BK);
#pragma unroll
            for (int i = 0; i < 2; i++) bfv[i] = *(const bf16_8*)(pb + i * 16 * BK);
#pragma unroll
            for (int mi = 0; mi < 4; mi++)
#pragma unroll
                for (int ni = 0; ni < 2; ni++)
                    acc[mi][ni] = __builtin_amdgcn_mfma_f32_16x16x32_bf16(
                        af[mi], bfv[ni], acc[mi][ni], 0, 0, 0);
        }
        if (t + 1 < NT) {
            asm volatile("s_waitcnt vmcnt(0)" ::: "memory");
            COMBINE_WRITE(t + 1);
            __syncthreads();
        }
    }
#undef LOAD_AB
#undef COMBINE_WRITE

#pragma unroll
    for (int mi = 0; mi < 4; mi++) {
#pragma unroll
        for (int ni = 0; ni < 2; ni++) {
            const int row0 = bm0 + wr * 64 + mi * 16 + hi * 4;
            const int col = bn0 + wc * 32 + ni * 16 + lo;
            const float bv = bias[col];
#pragma unroll
            for (int rr = 0; rr < 4; rr++) {
                const int m = row0 + rr;
                outp[(size_t)m * H_SIZE + col] =
                    acc[mi][ni][rr] + bv + resid[(size_t)m * H_SIZE + col];
            }
        }
    }
}

// ---------------- flash attention, split-K (z=2), QBLK=64/wave, XCD-swizzled ----------------
// grid: (SEQ/256, BATCH*N_HEADS, 2); remap so each XCD owns 4 bh's (K/V L2-resident).
__global__ __launch_bounds__(256) void attn_kernel(const ushort* __restrict__ Q,
                                                   const ushort* __restrict__ Ksw,
                                                   const ushort* __restrict__ Vsw,
                                                   ushort* __restrict__ Op0,
                                                   ushort* __restrict__ Op1,
                                                   float* __restrict__ Lpart) {
    __shared__ ushort Ks[3][64 * 64];   // 24 KB
    __shared__ ushort Vs[3][64 * 64];   // 24 KB
    const int lane = threadIdx.x & 63, wid = threadIdx.x >> 6;
    const int h32 = lane >> 5, q32 = lane & 31;

    // XCD-aware bijective remap: 256 (x,y) blocks per z = 8 XCDs x 32
    const int lin = blockIdx.y * gridDim.x + blockIdx.x;
    const int nlin = (lin & 7) * 32 + (lin >> 3);
    const int bx = nlin & 7;
    const int bh = nlin >> 3;            // 0..31
    const int z = blockIdx.z;
    const int q0w = bx * 256 + wid * 64;
    const int kbase = z * (SEQ / 2);
    const ushort* Qh = Q + (size_t)bh * SEQ * D_K;
    const ushort* Kp = Ksw + (size_t)bh * SEQ * D_K;
    const ushort* Vp = Vsw + (size_t)bh * D_K * SEQ;

    bf16_8 qfA[4], qfB[4];
#pragma unroll
    for (int tt = 0; tt < 4; tt++) {
        qfA[tt] = *(const bf16_8*)(Qh + (size_t)(q0w + q32) * D_K + tt * 16 + h32 * 8);
        qfB[tt] = *(const bf16_8*)(Qh + (size_t)(q0w + 32 + q32) * D_K + tt * 16 + h32 * 8);
    }

    f32x16 oA0 = {}, oA1 = {}, oB0 = {}, oB1 = {};
    float lsA = 0.f, lsB = 0.f;

    const int koff = wid * 2048 + lane * 16;
    const int vrow = wid * 16 + (lane >> 3);
    const int vseg = (lane & 7) * 16;

#define STAGE(bb, kt)                                                             \
    {                                                                             \
        const char* kg = (const char*)(Kp + (size_t)(kt) * D_K);                  \
        char* kl = (char*)&Ks[bb][0];                                             \
        gld16(kl + koff, kg + koff);                                              \
        gld16(kl + koff + 1024, kg + koff + 1024);                                \
        char* vl = (char*)&Vs[bb][0];                                             \
        gld16(vl + vrow * 128 + vseg,                                             \
              (const char*)(Vp + (size_t)vrow * SEQ + (kt)) + vseg);              \
        gld16(vl + (vrow + 8) * 128 + vseg,                                       \
              (const char*)(Vp + (size_t)(vrow + 8) * SEQ + (kt)) + vseg);        \
    }

    STAGE(0, kbase);
    STAGE(1, kbase + 64);
    asm volatile("s_waitcnt vmcnt(4)" ::: "memory");
    __builtin_amdgcn_s_barrier();
    __builtin_amdgcn_sched_barrier(0);

    constexpr int NTT = (SEQ / 2) / 64;  // 16 tiles per z
    int cur = 0;
    for (int t = 0; t < NTT; t++) {
        int c2 = cur + 2; if (c2 >= 3) c2 -= 3;
        if (t + 2 < NTT) STAGE(c2, kbase + (t + 2) * 64);
        const ushort* kb = &Ks[cur][0];
        const ushort* vb = &Vs[cur][0];
#pragma unroll
        for (int kh = 0; kh < 2; kh++) {
            f32x16 stA = {}, stB = {};
            const int krow = kh * 32 + q32;
            __builtin_amdgcn_s_setprio(1);
#pragma unroll
            for (int tt = 0; tt < 4; tt++) {
                int sg = (2 * tt + h32) ^ SWZ(krow);
                bf16_8 kf = *(const bf16_8*)(kb + krow * 64 + sg * 8);
                stA = __builtin_amdgcn_mfma_f32_32x32x16_bf16(kf, qfA[tt], stA, 0, 0, 0);
                stB = __builtin_amdgcn_mfma_f32_32x32x16_bf16(kf, qfB[tt], stB, 0, 0, 0);
            }
            __builtin_amdgcn_s_setprio(0);

            union { unsigned int w[4]; bf16_8 v; } pfA0, pfA1, pfB0, pfB1;
            float partA = 0.f, partB = 0.f;
#pragma unroll
            for (int i = 0; i < 2; i++) {
                float a0 = exp2_raw(stA[2 * i]),     a1 = exp2_raw(stA[2 * i + 1]);
                float a2 = exp2_raw(stA[4 + 2 * i]), a3 = exp2_raw(stA[4 + 2 * i + 1]);
                partA += (a0 + a1) + (a2 + a3);
                unsigned int ua = cvtpk(a0, a1), ub = cvtpk(a2, a3);
                asm volatile("v_permlane32_swap_b32 %0, %1" : "+v"(ua), "+v"(ub));
                pfA0.w[i] = ua; pfA0.w[2 + i] = ub;
                float a4 = exp2_raw(stA[8 + 2 * i]),  a5 = exp2_raw(stA[8 + 2 * i + 1]);
                float a6 = exp2_raw(stA[12 + 2 * i]), a7 = exp2_raw(stA[12 + 2 * i + 1]);
                partA += (a4 + a5) + (a6 + a7);
                unsigned int uc = cvtpk(a4, a5), ud = cvtpk(a6, a7);
                asm volatile("v_permlane32_swap_b32 %0, %1" : "+v"(uc), "+v"(ud));
                pfA1.w[i] = uc; pfA1.w[2 + i] = ud;
                float b0 = exp2_raw(stB[2 * i]),     b1 = exp2_raw(stB[2 * i + 1]);
                float b2 = exp2_raw(stB[4 + 2 * i]), b3 = exp2_raw(stB[4 + 2 * i + 1]);
                partB += (b0 + b1) + (b2 + b3);
                unsigned int ue = cvtpk(b0, b1), uf = cvtpk(b2, b3);
                asm volatile("v_permlane32_swap_b32 %0, %1" : "+v"(ue), "+v"(uf));
                pfB0.w[i] = ue; pfB0.w[2 + i] = uf;
                float b4 = exp2_raw(stB[8 + 2 * i]),  b5 = exp2_raw(stB[8 + 2 * i + 1]);
                float b6 = exp2_raw(stB[12 + 2 * i]), b7 = exp2_raw(stB[12 + 2 * i + 1]);
                partB += (b4 + b5) + (b6 + b7);
                unsigned int ug = cvtpk(b4, b5), uh = cvtpk(b6, b7);
                asm volatile("v_permlane32_swap_b32 %0, %1" : "+v"(ug), "+v"(uh));
                pfB1.w[i] = ug; pfB1.w[2 + i] = uh;
            }
            lsA += partA + __shfl_xor(partA, 32);
            lsB += partB + __shfl_xor(partB, 32);

            __builtin_amdgcn_s_setprio(1);
            {
                const int vr0 = q32;
                int sg0 = (4 * kh + h32) ^ SWZ(vr0);
                int sg1 = (4 * kh + 2 + h32) ^ SWZ(vr0);
                bf16_8 vf0 = *(const bf16_8*)(vb + vr0 * 64 + sg0 * 8);
                bf16_8 vf1 = *(const bf16_8*)(vb + vr0 * 64 + sg1 * 8);
                oA0 = __builtin_amdgcn_mfma_f32_32x32x16_bf16(pfA0.v, vf0, oA0, 0, 0, 0);
                oB0 = __builtin_amdgcn_mfma_f32_32x32x16_bf16(pfB0.v, vf0, oB0, 0, 0, 0);
                oA0 = __builtin_amdgcn_mfma_f32_32x32x16_bf16(pfA1.v, vf1, oA0, 0, 0, 0);
                oB0 = __builtin_amdgcn_mfma_f32_32x32x16_bf16(pfB1.v, vf1, oB0, 0, 0, 0);
            }
            {
                const int vr1 = 32 + q32;
                int sg0 = (4 * kh + h32) ^ SWZ(vr1);
                int sg1 = (4 * kh + 2 + h32) ^ SWZ(vr1);
                bf16_8 vf0 = *(const bf16_8*)(vb + vr1 * 64 + sg0 * 8);
                bf16_8 vf1 = *(const bf16_8*)(vb + vr1 * 64 + sg1 * 8);
                oA1 = __builtin_amdgcn_mfma_f32_32x32x16_bf16(pfA0.v, vf0, oA1, 0, 0, 0);
                oB1 = __builtin_amdgcn_mfma_f32_32x32x16_bf16(pfB0.v, vf0, oB1, 0, 0, 0);
                oA1 = __builtin_amdgcn_mfma_f32_32x32x16_bf16(pfA1.v, vf1, oA1, 0, 0, 0);
                oB1 = __builtin_amdgcn_mfma_f32_32x32x16_bf16(pfB1.v, vf1, oB1, 0, 0, 0);
            }
            __builtin_amdgcn_s_setprio(0);
        }
        if (t + 1 < NTT) {
            if (t + 2 < NTT) { asm volatile("s_waitcnt vmcnt(4)" ::: "memory"); }
            else             { asm volatile("s_waitcnt vmcnt(0)" ::: "memory"); }
            __builtin_amdgcn_s_barrier();
            __builtin_amdgcn_sched_barrier(0);
        }
        cur = cur + 1; if (cur >= 3) cur -= 3;
    }
#undef STAGE

    ushort* Op = (z == 0) ? Op0 : Op1;
    float* Lp = Lpart + (size_t)z * N_HEADS * BATCH * SEQ;
    const int b = bh >> 4, h = bh & 15;
#pragma unroll
    for (int rr = 0; rr < 16; rr++) {
        const int qloc = (rr & 3) + 8 * (rr >> 2) + 4 * h32;
        const int lA = q0w + qloc;
        ushort* orowA = Op + ((size_t)(b * SEQ + lA)) * H_SIZE + h * 64;
        orowA[q32] = f2bf(oA0[rr]);
        orowA[32 + q32] = f2bf(oA1[rr]);
        const int lB = q0w + 32 + qloc;
        ushort* orowB = Op + ((size_t)(b * SEQ + lB)) * H_SIZE + h * 64;
        orowB[q32] = f2bf(oB0[rr]);
        orowB[32 + q32] = f2bf(oB1[rr]);
    }
    if (lane < 32) {
        Lp[(size_t)bh * SEQ + q0w + q32] = lsA;
        Lp[(size_t)bh * SEQ + q0w + 32 + q32] = lsB;
    }
}

// ---------------- LayerNorm in-place on d_out ----------------
__global__ __launch_bounds__(256) void ln_kernel(float* __restrict__ y,
                                                 const float* __restrict__ gamma,
                                                 const float* __restrict__ beta) {
    const int row = blockIdx.x;
    float4* p = (float4*)(y + (size_t)row * H_SIZE);
    float4 v = p[threadIdx.x];
    float s = v.x + v.y + v.z + v.w;
    float s2 = v.x * v.x + v.y * v.y + v.z * v.z + v.w * v.w;
#pragma unroll
    for (int off = 1; off < 64; off <<= 1) {
        s += __shfl_xor(s, off);
        s2 += __shfl_xor(s2, off);
    }
    __shared__ float ss[4], ss2[4];
    const int wid = threadIdx.x >> 6, lane = threadIdx.x & 63;
    if (lane == 0) { ss[wid] = s; ss2[wid] = s2; }
    __syncthreads();
    s = ss[0] + ss[1] + ss[2] + ss[3];
    s2 = ss2[0] + ss2[1] + ss2[2] + ss2[3];
    const float mean = s * (1.0f / H_SIZE);
    const float var = s2 * (1.0f / H_SIZE) - mean * mean;
    const float rstd = rsqrtf(var + 1e-5f);
    const float4 g = ((const float4*)gamma)[threadIdx.x];
    const float4 bt = ((const float4*)beta)[threadIdx.x];
    float4 o;
    o.x = (v.x - mean) * rstd * g.x + bt.x;
    o.y = (v.y - mean) * rstd * g.y + bt.y;
    o.z = (v.z - mean) * rstd * g.z + bt.z;
    o.w = (v.w - mean) * rstd * g.w + bt.w;
    p[threadIdx.x] = o;
}

extern "C" void kernel_launch(void* const* d_in, const int* in_sizes, int n_in,
                              void* d_out, int out_size, void* d_ws, size_t ws_size,
                              hipStream_t stream) {
    const float* x = (const float*)d_in[0];
    const float* Wq = (const float*)d_in[1];
    const float* bq = (const float*)d_in[2];
    const float* Wk = (const float*)d_in[3];
    const float* bk = (const float*)d_in[4];
    const float* Wv = (const float*)d_in[5];
    const float* bv = (const float*)d_in[6];
    const float* Wo = (const float*)d_in[7];
    const float* bo = (const float*)d_in[8];
    const float* gamma = (const float*)d_in[9];
    const float* beta = (const float*)d_in[10];

    char* ws = (char*)d_ws;
    ushort* xb  = (ushort*)(ws);                    // 8 MB: x bf16 (dead after qkv -> Op0)
    ushort* wqb = (ushort*)(ws + (8u << 20));       // 2 MB each
    ushort* wkb = (ushort*)(ws + (10u << 20));
    ushort* wvb = (ushort*)(ws + (12u << 20));
    ushort* wob = (ushort*)(ws + (14u << 20));      // LIVE until gemm_o — do not clobber
    ushort* Qb  = (ushort*)(ws + (16u << 20));      // 8 MB [b,h,l,dk] (x 0.125*log2e)
    ushort* Kb  = (ushort*)(ws + (24u << 20));      // 8 MB [b,h,l,dk] SWZ-swizzled
    ushort* Vtb = (ushort*)(ws + (32u << 20));      // 8 MB [b,h,dk,l] SWZ-swizzled
    ushort* Op0 = (ushort*)(ws);                    // 8 MB partial O (z=0), reuses xb
    ushort* Op1 = (ushort*)(ws + (40u << 20));      // 8 MB partial O (z=1)
    float*  Lpt = (float*)(ws + (48u << 20));       // 512 KB partial row-sums [2][32][2048]

    cast_all_kernel<<<8192, 256, 0, stream>>>(x, Wq, Wk, Wv, Wo, xb, wqb, wkb, wvb, wob);

    dim3 gq(M_TOT / 128, 24);
    gemm_qkv<<<gq, 256, 0, stream>>>(xb, wqb, wkb, wvb, bq, bk, bv, Qb, Kb, Vtb);

    dim3 g2(SEQ / 256, BATCH * N_HEADS, 2);
    attn_kernel<<<g2, 256, 0, stream>>>(Qb, Kb, Vtb, Op0, Op1, Lpt);

    dim3 go(M_TOT / 128, H_SIZE / 64);
    gemm_o<<<go, 256, 0, stream>>>(Op0, Op1, Lpt, wob, bo, x, (float*)d_out);

    ln_kernel<<<M_TOT, 256, 0, stream>>>((float*)d_out, gamma, beta);
}

// Round 14
// 136.265 us; speedup vs baseline: 1.1183x; 1.1183x over previous
//
#include <hip/hip_runtime.h>

#define H_SIZE 1024
#define N_HEADS 16
#define D_K 64
#define SEQ 2048
#define BATCH 2
#define M_TOT 4096  // BATCH*SEQ

typedef __bf16 __attribute__((ext_vector_type(8))) bf16_8;
typedef float __attribute__((ext_vector_type(4))) f32x4;
typedef float __attribute__((ext_vector_type(16))) f32x16;
typedef int __attribute__((ext_vector_type(4))) int4v;

// row-swizzle for 128B-row LDS tiles (attn): spread rows sharing (r&7) across segments
#define SWZ(r) ((((r) & 7) ^ (((r) >> 3) & 7)))

__device__ __forceinline__ ushort f2bf(float f) {
    unsigned int u = __float_as_uint(f);
    unsigned int r = (u + 0x7FFFu + ((u >> 16) & 1u)) >> 16;
    return (ushort)r;
}

__device__ __forceinline__ unsigned int cvtpk(float lo, float hi) {
    unsigned int r;
    asm("v_cvt_pk_bf16_f32 %0, %1, %2" : "=v"(r) : "v"(lo), "v"(hi));
    return r;
}

__device__ __forceinline__ float exp2_raw(float x) {
    float r;
    asm("v_exp_f32 %0, %1" : "=v"(r) : "v"(x));
    return r;
}

__device__ __forceinline__ void gld16(void* lds, const void* g) {
    __builtin_amdgcn_global_load_lds(
        (const __attribute__((address_space(1))) unsigned int*)g,
        (__attribute__((address_space(3))) unsigned int*)lds, 16, 0, 0);
}

// ---------------- fused cast fp32 -> bf16 for x + 4 weight matrices ----------------
__global__ __launch_bounds__(256) void cast_all_kernel(
    const float* __restrict__ x, const float* __restrict__ wq, const float* __restrict__ wk,
    const float* __restrict__ wv, const float* __restrict__ wo,
    ushort* __restrict__ xb, ushort* __restrict__ wqb, ushort* __restrict__ wkb,
    ushort* __restrict__ wvb, ushort* __restrict__ wob) {
    int i = blockIdx.x * 256 + threadIdx.x;  // float4 index
    const float* src;
    ushort* dst;
    int off;
    if (i < 1048576) {          // x: 4096*1024/4
        src = x; dst = xb; off = i;
    } else {
        int j = i - 1048576;    // each W: 1024*1024/4 = 262144
        int w = j >> 18;
        off = j & 262143;
        src = (w == 0) ? wq : (w == 1) ? wk : (w == 2) ? wv : wo;
        dst = (w == 0) ? wqb : (w == 1) ? wkb : (w == 2) ? wvb : wob;
    }
    float4 v = ((const float4*)src)[off];
    ushort4 o;
    o.x = f2bf(v.x); o.y = f2bf(v.y); o.z = f2bf(v.z); o.w = f2bf(v.w);
    ((ushort4*)dst)[off] = o;
}

// ---------------- fused QKV GEMM: triple-buffered BK=32, counted vmcnt, gld16 (r8) ----------------
__global__ __launch_bounds__(256) void gemm_qkv(
    const ushort* __restrict__ A, const ushort* __restrict__ wq,
    const ushort* __restrict__ wk, const ushort* __restrict__ wv,
    const float* __restrict__ bq, const float* __restrict__ bk, const float* __restrict__ bv,
    ushort* __restrict__ Qb, ushort* __restrict__ Kb, ushort* __restrict__ Vtb) {
    constexpr int BK = 32;
    __shared__ ushort As[3][128 * BK];   // 24 KB
    __shared__ ushort Bs[3][128 * BK];   // 24 KB
    const int tid = threadIdx.x;
    const int lane = tid & 63, wid = tid >> 6;
    const int wr = wid >> 1, wc = wid & 1;
    const int hi = lane >> 4, lo = lane & 15;
    const int bm0 = blockIdx.x * 128;
    const int t3 = blockIdx.y >> 3;
    const int bn0 = (blockIdx.y & 7) * 128;
    const ushort* Bw = (t3 == 0) ? wq : (t3 == 1) ? wk : wv;
    const float* bias = (t3 == 0) ? bq : (t3 == 1) ? bk : bv;

    f32x4 acc[4][4] = {};

    const int srow = tid >> 2;
    const int sseg = ((tid & 3) ^ ((tid >> 3) & 3)) * 8;  // ushort offset
    const ushort* gaB = A + (size_t)(bm0 + srow) * H_SIZE + sseg;
    const ushort* gbB = Bw + (size_t)(bn0 + srow) * H_SIZE + sseg;
    const int ldsOff = tid * 16;  // bytes

#define STAGE(ba, bb, kt)                                 \
    {                                                     \
        char* la = (char*)(ba) + ldsOff;                  \
        char* lb = (char*)(bb) + ldsOff;                  \
        gld16(la, gaB + (kt));                            \
        gld16(la + 4096, gaB + 64 * H_SIZE + (kt));       \
        gld16(lb, gbB + (kt));                            \
        gld16(lb + 4096, gbB + 64 * H_SIZE + (kt));       \
    }

    STAGE(&As[0][0], &Bs[0][0], 0);
    STAGE(&As[1][0], &Bs[1][0], BK);
    asm volatile("s_waitcnt vmcnt(4)" ::: "memory");
    __builtin_amdgcn_s_barrier();
    __builtin_amdgcn_sched_barrier(0);

    constexpr int NT = H_SIZE / BK;  // 32
    const int rxv = (lo >> 1) & 3;   // read-side swizzle term
    int cur = 0;
    for (int t = 0; t < NT; t++) {
        int c2 = cur + 2; if (c2 >= 3) c2 -= 3;
        if (t + 2 < NT) STAGE(&As[c2][0], &Bs[c2][0], (t + 2) * BK);
        {
            bf16_8 af[4], bfv[4];
            const ushort* pa = &As[cur][(wr * 64 + lo) * BK + ((hi ^ rxv) * 8)];
            const ushort* pb = &Bs[cur][(wc * 64 + lo) * BK + ((hi ^ rxv) * 8)];
#pragma unroll
            for (int i = 0; i < 4; i++) af[i] = *(const bf16_8*)(pa + i * 16 * BK);
#pragma unroll
            for (int i = 0; i < 4; i++) bfv[i] = *(const bf16_8*)(pb + i * 16 * BK);
#pragma unroll
            for (int mi = 0; mi < 4; mi++)
#pragma unroll
                for (int ni = 0; ni < 4; ni++)
                    acc[mi][ni] = __builtin_amdgcn_mfma_f32_16x16x32_bf16(
                        af[mi], bfv[ni], acc[mi][ni], 0, 0, 0);
        }
        if (t + 1 < NT) {
            if (t + 2 < NT) { asm volatile("s_waitcnt vmcnt(4)" ::: "memory"); }
            else            { asm volatile("s_waitcnt vmcnt(0)" ::: "memory"); }
            __builtin_amdgcn_s_barrier();
            __builtin_amdgcn_sched_barrier(0);
        }
        cur = cur + 1; if (cur >= 3) cur -= 3;
    }
#undef STAGE

#pragma unroll
    for (int mi = 0; mi < 4; mi++) {
#pragma unroll
        for (int ni = 0; ni < 4; ni++) {
            const int row0 = bm0 + wr * 64 + mi * 16 + hi * 4;
            const int col = bn0 + wc * 64 + ni * 16 + lo;
            const float bv = bias[col];
            const int h = col >> 6, dk = col & 63;
            if (t3 == 2) {
                const int b = row0 >> 11, l0 = row0 & 2047;
                const int lsw0 = (l0 & ~63) | (((((l0 >> 3) & 7) ^ SWZ(dk)) & 7) << 3) | (l0 & 7);
                uint2 o;
                o.x = cvtpk(acc[mi][ni][0] + bv, acc[mi][ni][1] + bv);
                o.y = cvtpk(acc[mi][ni][2] + bv, acc[mi][ni][3] + bv);
                *(uint2*)&Vtb[((size_t)(b * N_HEADS + h) * D_K + dk) * SEQ + lsw0] = o;
            } else {
#pragma unroll
                for (int rr = 0; rr < 4; rr++) {
                    const int m = row0 + rr;
                    const int b = m >> 11, l = m & 2047;
                    float val = acc[mi][ni][rr] + bv;
                    if (t3 == 0) {
                        Qb[((size_t)(b * N_HEADS + h) * SEQ + l) * D_K + dk] =
                            f2bf(val * 0.18033688f);
                    } else {
                        int dks = ((((dk >> 3) ^ SWZ(l & 63)) & 7) << 3) | (dk & 7);
                        Kb[((size_t)(b * N_HEADS + h) * SEQ + l) * D_K + dks] = f2bf(val);
                    }
                }
            }
        }
    }
}

// ---------------- O-projection GEMM 128x64: triple-buffered BK=32, counted vmcnt (r8) ----------------
__global__ __launch_bounds__(256) void gemm_o(const ushort* __restrict__ A,
                                              const ushort* __restrict__ Bw,
                                              const float* __restrict__ bias,
                                              const float* __restrict__ resid,
                                              float* __restrict__ outp) {
    constexpr int BK = 32;
    __shared__ ushort As[3][128 * BK];  // 24 KB
    __shared__ ushort Bs[3][64 * BK];   // 12 KB
    const int tid = threadIdx.x;
    const int lane = tid & 63, wid = tid >> 6;
    const int wr = wid >> 1, wc = wid & 1;
    const int hi = lane >> 4, lo = lane & 15;
    const int bm0 = blockIdx.x * 128, bn0 = blockIdx.y * 64;

    f32x4 acc[4][2] = {};

    const int srow = tid >> 2;
    const int sseg = ((tid & 3) ^ ((tid >> 3) & 3)) * 8;
    const ushort* gaB = A + (size_t)(bm0 + srow) * H_SIZE + sseg;
    const ushort* gbB = Bw + (size_t)(bn0 + srow) * H_SIZE + sseg;
    const int ldsOff = tid * 16;

#define STAGE(ba, bb, kt)                                 \
    {                                                     \
        char* la = (char*)(ba) + ldsOff;                  \
        gld16(la, gaB + (kt));                            \
        gld16(la + 4096, gaB + 64 * H_SIZE + (kt));       \
        gld16((char*)(bb) + ldsOff, gbB + (kt));          \
    }

    STAGE(&As[0][0], &Bs[0][0], 0);
    STAGE(&As[1][0], &Bs[1][0], BK);
    asm volatile("s_waitcnt vmcnt(3)" ::: "memory");
    __builtin_amdgcn_s_barrier();
    __builtin_amdgcn_sched_barrier(0);

    constexpr int NT = H_SIZE / BK;
    const int rxv = (lo >> 1) & 3;
    int cur = 0;
    for (int t = 0; t < NT; t++) {
        int c2 = cur + 2; if (c2 >= 3) c2 -= 3;
        if (t + 2 < NT) STAGE(&As[c2][0], &Bs[c2][0], (t + 2) * BK);
        {
            bf16_8 af[4], bfv[2];
            const ushort* pa = &As[cur][(wr * 64 + lo) * BK + ((hi ^ rxv) * 8)];
            const ushort* pb = &Bs[cur][(wc * 32 + lo) * BK + ((hi ^ rxv) * 8)];
#pragma unroll
            for (int i = 0; i < 4; i++) af[i] = *(const bf16_8*)(pa + i * 16 * BK);
#pragma unroll
            for (int i = 0; i < 2; i++) bfv[i] = *(const bf16_8*)(pb + i * 16 * BK);
#pragma unroll
            for (int mi = 0; mi < 4; mi++)
#pragma unroll
                for (int ni = 0; ni < 2; ni++)
                    acc[mi][ni] = __builtin_amdgcn_mfma_f32_16x16x32_bf16(
                        af[mi], bfv[ni], acc[mi][ni], 0, 0, 0);
        }
        if (t + 1 < NT) {
            if (t + 2 < NT) { asm volatile("s_waitcnt vmcnt(3)" ::: "memory"); }
            else            { asm volatile("s_waitcnt vmcnt(0)" ::: "memory"); }
            __builtin_amdgcn_s_barrier();
            __builtin_amdgcn_sched_barrier(0);
        }
        cur = cur + 1; if (cur >= 3) cur -= 3;
    }
#undef STAGE

#pragma unroll
    for (int mi = 0; mi < 4; mi++) {
#pragma unroll
        for (int ni = 0; ni < 2; ni++) {
            const int row0 = bm0 + wr * 64 + mi * 16 + hi * 4;
            const int col = bn0 + wc * 32 + ni * 16 + lo;
            const float bv = bias[col];
#pragma unroll
            for (int rr = 0; rr < 4; rr++) {
                const int m = row0 + rr;
                outp[(size_t)m * H_SIZE + col] =
                    acc[mi][ni][rr] + bv + resid[(size_t)m * H_SIZE + col];
            }
        }
    }
}

// ---------------- flash attention: z=1, QBLK=32/wave, kh-interleaved, XCD-swizzled ----------------
// grid (16, 32) = 512 blocks. Both QK halves' MFMAs issue before softmax-0 so the VALU
// softmax overlaps in-flight MFMAs (dual-pipe); PV0 overlaps softmax-1. VALU row-sum +
// lsum_lds redistribution (r8-proven). Direct divided bf16 write to Ao.
__global__ __launch_bounds__(256) void attn_kernel(const ushort* __restrict__ Q,
                                                   const ushort* __restrict__ Ksw,
                                                   const ushort* __restrict__ Vsw,
                                                   ushort* __restrict__ Out) {
    __shared__ ushort Ks[3][64 * 64];   // 24 KB
    __shared__ ushort Vs[3][64 * 64];   // 24 KB
    __shared__ float lsum_lds[4][32];
    const int lane = threadIdx.x & 63, wid = threadIdx.x >> 6;
    const int h32 = lane >> 5, q32 = lane & 31;

    // XCD-aware bijective remap: 512 blocks = 8 XCDs x 64 -> 4 heads per XCD (K/V 2MB L2-fit)
    const int lin = blockIdx.y * gridDim.x + blockIdx.x;
    const int nlin = (lin & 7) * 64 + (lin >> 3);
    const int bx = nlin & 15;
    const int bh = nlin >> 4;            // 0..31
    const int q0 = bx * 128 + wid * 32;
    const ushort* Qh = Q + (size_t)bh * SEQ * D_K;
    const ushort* Kp = Ksw + (size_t)bh * SEQ * D_K;
    const ushort* Vp = Vsw + (size_t)bh * D_K * SEQ;

    bf16_8 qf[4];
#pragma unroll
    for (int tt = 0; tt < 4; tt++)
        qf[tt] = *(const bf16_8*)(Qh + (size_t)(q0 + q32) * D_K + tt * 16 + h32 * 8);

    f32x16 oacc0 = {}, oacc1 = {};
    float ls = 0.f;

    const int koff = wid * 2048 + lane * 16;
    const int vrow = wid * 16 + (lane >> 3);
    const int vseg = (lane & 7) * 16;

#define STAGE(bb, kt)                                                             \
    {                                                                             \
        const char* kg = (const char*)(Kp + (size_t)(kt) * D_K);                  \
        char* kl = (char*)&Ks[bb][0];                                             \
        gld16(kl + koff, kg + koff);                                              \
        gld16(kl + koff + 1024, kg + koff + 1024);                                \
        char* vl = (char*)&Vs[bb][0];                                             \
        gld16(vl + vrow * 128 + vseg,                                             \
              (const char*)(Vp + (size_t)vrow * SEQ + (kt)) + vseg);              \
        gld16(vl + (vrow + 8) * 128 + vseg,                                       \
              (const char*)(Vp + (size_t)(vrow + 8) * SEQ + (kt)) + vseg);        \
    }

    STAGE(0, 0);
    STAGE(1, 64);
    asm volatile("s_waitcnt vmcnt(4)" ::: "memory");
    __builtin_amdgcn_s_barrier();
    __builtin_amdgcn_sched_barrier(0);

    constexpr int NTT = SEQ / 64;  // 32
    int cur = 0;
    for (int t = 0; t < NTT; t++) {
        int c2 = cur + 2; if (c2 >= 3) c2 -= 3;
        if (t + 2 < NTT) STAGE(c2, (t + 2) * 64);
        const ushort* kb = &Ks[cur][0];
        const ushort* vb = &Vs[cur][0];

        // --- QK both halves back-to-back (independent MFMA chains fill the pipe) ---
        f32x16 st0 = {}, st1 = {};
        __builtin_amdgcn_s_setprio(1);
#pragma unroll
        for (int tt = 0; tt < 4; tt++) {
            const int krow = q32;
            int sg = (2 * tt + h32) ^ SWZ(krow);
            bf16_8 kf = *(const bf16_8*)(kb + krow * 64 + sg * 8);
            st0 = __builtin_amdgcn_mfma_f32_32x32x16_bf16(kf, qf[tt], st0, 0, 0, 0);
        }
#pragma unroll
        for (int tt = 0; tt < 4; tt++) {
            const int krow = 32 + q32;
            int sg = (2 * tt + h32) ^ SWZ(krow);
            bf16_8 kf = *(const bf16_8*)(kb + krow * 64 + sg * 8);
            st1 = __builtin_amdgcn_mfma_f32_32x32x16_bf16(kf, qf[tt], st1, 0, 0, 0);
        }
        __builtin_amdgcn_s_setprio(0);

        // --- softmax-0 (overlaps st1's in-flight MFMAs) ---
        union { unsigned int w[4]; bf16_8 v; } pf00, pf01;
        float part0 = 0.f;
#pragma unroll
        for (int rr = 0; rr < 16; rr++) { st0[rr] = exp2_raw(st0[rr]); part0 += st0[rr]; }
#pragma unroll
        for (int i = 0; i < 2; i++) {
            unsigned int a = cvtpk(st0[2 * i], st0[2 * i + 1]);
            unsigned int b = cvtpk(st0[4 + 2 * i], st0[4 + 2 * i + 1]);
            asm volatile("v_permlane32_swap_b32 %0, %1" : "+v"(a), "+v"(b));
            pf00.w[i] = a; pf00.w[2 + i] = b;
            unsigned int c = cvtpk(st0[8 + 2 * i], st0[8 + 2 * i + 1]);
            unsigned int d = cvtpk(st0[12 + 2 * i], st0[12 + 2 * i + 1]);
            asm volatile("v_permlane32_swap_b32 %0, %1" : "+v"(c), "+v"(d));
            pf01.w[i] = c; pf01.w[2 + i] = d;
        }
        ls += part0 + __shfl_xor(part0, 32);

        // --- PV-0 (MFMA; overlaps softmax-1 VALU below) ---
        __builtin_amdgcn_s_setprio(1);
        {
            const int vr0 = q32;
            int sg0 = (h32) ^ SWZ(vr0);
            int sg1 = (2 + h32) ^ SWZ(vr0);
            bf16_8 vf0 = *(const bf16_8*)(vb + vr0 * 64 + sg0 * 8);
            bf16_8 vf1 = *(const bf16_8*)(vb + vr0 * 64 + sg1 * 8);
            oacc0 = __builtin_amdgcn_mfma_f32_32x32x16_bf16(pf00.v, vf0, oacc0, 0, 0, 0);
            oacc0 = __builtin_amdgcn_mfma_f32_32x32x16_bf16(pf01.v, vf1, oacc0, 0, 0, 0);
            const int vr1 = 32 + q32;
            int sg2 = (h32) ^ SWZ(vr1);
            int sg3 = (2 + h32) ^ SWZ(vr1);
            bf16_8 vf2 = *(const bf16_8*)(vb + vr1 * 64 + sg2 * 8);
            bf16_8 vf3 = *(const bf16_8*)(vb + vr1 * 64 + sg3 * 8);
            oacc1 = __builtin_amdgcn_mfma_f32_32x32x16_bf16(pf00.v, vf2, oacc1, 0, 0, 0);
            oacc1 = __builtin_amdgcn_mfma_f32_32x32x16_bf16(pf01.v, vf3, oacc1, 0, 0, 0);
        }
        __builtin_amdgcn_s_setprio(0);

        // --- softmax-1 ---
        union { unsigned int w[4]; bf16_8 v; } pf10, pf11;
        float part1 = 0.f;
#pragma unroll
        for (int rr = 0; rr < 16; rr++) { st1[rr] = exp2_raw(st1[rr]); part1 += st1[rr]; }
#pragma unroll
        for (int i = 0; i < 2; i++) {
            unsigned int a = cvtpk(st1[2 * i], st1[2 * i + 1]);
            unsigned int b = cvtpk(st1[4 + 2 * i], st1[4 + 2 * i + 1]);
            asm volatile("v_permlane32_swap_b32 %0, %1" : "+v"(a), "+v"(b));
            pf10.w[i] = a; pf10.w[2 + i] = b;
            unsigned int c = cvtpk(st1[8 + 2 * i], st1[8 + 2 * i + 1]);
            unsigned int d = cvtpk(st1[12 + 2 * i], st1[12 + 2 * i + 1]);
            asm volatile("v_permlane32_swap_b32 %0, %1" : "+v"(c), "+v"(d));
            pf11.w[i] = c; pf11.w[2 + i] = d;
        }
        ls += part1 + __shfl_xor(part1, 32);

        // --- PV-1 ---
        __builtin_amdgcn_s_setprio(1);
        {
            const int vr0 = q32;
            int sg0 = (4 + h32) ^ SWZ(vr0);
            int sg1 = (6 + h32) ^ SWZ(vr0);
            bf16_8 vf0 = *(const bf16_8*)(vb + vr0 * 64 + sg0 * 8);
            bf16_8 vf1 = *(const bf16_8*)(vb + vr0 * 64 + sg1 * 8);
            oacc0 = __builtin_amdgcn_mfma_f32_32x32x16_bf16(pf10.v, vf0, oacc0, 0, 0, 0);
            oacc0 = __builtin_amdgcn_mfma_f32_32x32x16_bf16(pf11.v, vf1, oacc0, 0, 0, 0);
            const int vr1 = 32 + q32;
            int sg2 = (4 + h32) ^ SWZ(vr1);
            int sg3 = (6 + h32) ^ SWZ(vr1);
            bf16_8 vf2 = *(const bf16_8*)(vb + vr1 * 64 + sg2 * 8);
            bf16_8 vf3 = *(const bf16_8*)(vb + vr1 * 64 + sg3 * 8);
            oacc1 = __builtin_amdgcn_mfma_f32_32x32x16_bf16(pf10.v, vf2, oacc1, 0, 0, 0);
            oacc1 = __builtin_amdgcn_mfma_f32_32x32x16_bf16(pf11.v, vf3, oacc1, 0, 0, 0);
        }
        __builtin_amdgcn_s_setprio(0);

        if (t + 1 < NTT) {
            if (t + 2 < NTT) { asm volatile("s_waitcnt vmcnt(4)" ::: "memory"); }
            else             { asm volatile("s_waitcnt vmcnt(0)" ::: "memory"); }
            __builtin_amdgcn_s_barrier();
            __builtin_amdgcn_sched_barrier(0);
        }
        cur = cur + 1; if (cur >= 3) cur -= 3;
    }
#undef STAGE

    if (lane < 32) lsum_lds[wid][q32] = 1.0f / ls;
    const int b = bh >> 4, h = bh & 15;
#pragma unroll
    for (int rr = 0; rr < 16; rr++) {
        const int qloc = (rr & 3) + 8 * (rr >> 2) + 4 * h32;
        const float inv = lsum_lds[wid][qloc];
        const int l = q0 + qloc;
        ushort* orow = Out + ((size_t)(b * SEQ + l)) * H_SIZE + h * 64;
        orow[q32] = f2bf(oacc0[rr] * inv);
        orow[32 + q32] = f2bf(oacc1[rr] * inv);
    }
}

// ---------------- LayerNorm in-place on d_out ----------------
__global__ __launch_bounds__(256) void ln_kernel(float* __restrict__ y,
                                                 const float* __restrict__ gamma,
                                                 const float* __restrict__ beta) {
    const int row = blockIdx.x;
    float4* p = (float4*)(y + (size_t)row * H_SIZE);
    float4 v = p[threadIdx.x];
    float s = v.x + v.y + v.z + v.w;
    float s2 = v.x * v.x + v.y * v.y + v.z * v.z + v.w * v.w;
#pragma unroll
    for (int off = 1; off < 64; off <<= 1) {
        s += __shfl_xor(s, off);
        s2 += __shfl_xor(s2, off);
    }
    __shared__ float ss[4], ss2[4];
    const int wid = threadIdx.x >> 6, lane = threadIdx.x & 63;
    if (lane == 0) { ss[wid] = s; ss2[wid] = s2; }
    __syncthreads();
    s = ss[0] + ss[1] + ss[2] + ss[3];
    s2 = ss2[0] + ss2[1] + ss2[2] + ss2[3];
    const float mean = s * (1.0f / H_SIZE);
    const float var = s2 * (1.0f / H_SIZE) - mean * mean;
    const float rstd = rsqrtf(var + 1e-5f);
    const float4 g = ((const float4*)gamma)[threadIdx.x];
    const float4 bt = ((const float4*)beta)[threadIdx.x];
    float4 o;
    o.x = (v.x - mean) * rstd * g.x + bt.x;
    o.y = (v.y - mean) * rstd * g.y + bt.y;
    o.z = (v.z - mean) * rstd * g.z + bt.z;
    o.w = (v.w - mean) * rstd * g.w + bt.w;
    p[threadIdx.x] = o;
}

extern "C" void kernel_launch(void* const* d_in, const int* in_sizes, int n_in,
                              void* d_out, int out_size, void* d_ws, size_t ws_size,
                              hipStream_t stream) {
    const float* x = (const float*)d_in[0];
    const float* Wq = (const float*)d_in[1];
    const float* bq = (const float*)d_in[2];
    const float* Wk = (const float*)d_in[3];
    const float* bk = (const float*)d_in[4];
    const float* Wv = (const float*)d_in[5];
    const float* bv = (const float*)d_in[6];
    const float* Wo = (const float*)d_in[7];
    const float* bo = (const float*)d_in[8];
    const float* gamma = (const float*)d_in[9];
    const float* beta = (const float*)d_in[10];

    char* ws = (char*)d_ws;
    ushort* xb  = (ushort*)(ws);                    // 8 MB: x bf16
    ushort* wqb = (ushort*)(ws + (8u << 20));       // 2 MB each
    ushort* wkb = (ushort*)(ws + (10u << 20));
    ushort* wvb = (ushort*)(ws + (12u << 20));
    ushort* wob = (ushort*)(ws + (14u << 20));      // LIVE until gemm_o
    ushort* Qb  = (ushort*)(ws + (16u << 20));      // 8 MB [b,h,l,dk] (x 0.125*log2e)
    ushort* Kb  = (ushort*)(ws + (24u << 20));      // 8 MB [b,h,l,dk] SWZ-swizzled
    ushort* Vtb = (ushort*)(ws + (32u << 20));      // 8 MB [b,h,dk,l] SWZ-swizzled
    ushort* Ao  = (ushort*)(ws + (40u << 20));      // 8 MB attn out bf16 [m,H]

    cast_all_kernel<<<8192, 256, 0, stream>>>(x, Wq, Wk, Wv, Wo, xb, wqb, wkb, wvb, wob);

    dim3 gq(M_TOT / 128, 24);
    gemm_qkv<<<gq, 256, 0, stream>>>(xb, wqb, wkb, wvb, bq, bk, bv, Qb, Kb, Vtb);

    dim3 g2(SEQ / 128, BATCH * N_HEADS);
    attn_kernel<<<g2, 256, 0, stream>>>(Qb, Kb, Vtb, Ao);

    dim3 go(M_TOT / 128, H_SIZE / 64);
    gemm_o<<<go, 256, 0, stream>>>(Ao, wob, bo, x, (float*)d_out);

    ln_kernel<<<M_TOT, 256, 0, stream>>>((float*)d_out, gamma, beta);
}

// Round 15
// 132.335 us; speedup vs baseline: 1.1515x; 1.0297x over previous
//
#include <hip/hip_runtime.h>

#define H_SIZE 1024
#define N_HEADS 16
#define D_K 64
#define SEQ 2048
#define BATCH 2
#define M_TOT 4096  // BATCH*SEQ

typedef __bf16 __attribute__((ext_vector_type(8))) bf16_8;
typedef float __attribute__((ext_vector_type(4))) f32x4;
typedef float __attribute__((ext_vector_type(16))) f32x16;
typedef int __attribute__((ext_vector_type(4))) int4v;

// row-swizzle for 128B-row LDS tiles (attn): spread rows sharing (r&7) across segments
#define SWZ(r) ((((r) & 7) ^ (((r) >> 3) & 7)))

__device__ __forceinline__ ushort f2bf(float f) {
    unsigned int u = __float_as_uint(f);
    unsigned int r = (u + 0x7FFFu + ((u >> 16) & 1u)) >> 16;
    return (ushort)r;
}

__device__ __forceinline__ unsigned int cvtpk(float lo, float hi) {
    unsigned int r;
    asm("v_cvt_pk_bf16_f32 %0, %1, %2" : "=v"(r) : "v"(lo), "v"(hi));
    return r;
}

__device__ __forceinline__ float exp2_raw(float x) {
    float r;
    asm("v_exp_f32 %0, %1" : "=v"(r) : "v"(x));
    return r;
}

__device__ __forceinline__ void gld16(void* lds, const void* g) {
    __builtin_amdgcn_global_load_lds(
        (const __attribute__((address_space(1))) unsigned int*)g,
        (__attribute__((address_space(3))) unsigned int*)lds, 16, 0, 0);
}

// ---------------- fused QKV GEMM: fp32 inputs, in-register cvt, 2-buffer write-late ----------------
// Reads x and Wq/Wk/Wv directly in fp32 (no cast kernel); converts to bf16 during LDS staging.
// grid (32, 24): blockIdx.y>>3 selects {Q,K,V}. Natural block order (r12 lesson).
__global__ __launch_bounds__(256) void gemm_qkv(
    const float* __restrict__ X, const float* __restrict__ Wqf,
    const float* __restrict__ Wkf, const float* __restrict__ Wvf,
    const float* __restrict__ bq, const float* __restrict__ bk, const float* __restrict__ bv,
    ushort* __restrict__ Qb, ushort* __restrict__ Kb, ushort* __restrict__ Vtb) {
    constexpr int BK = 32;
    __shared__ ushort As[2][128 * BK];   // 16 KB
    __shared__ ushort Bs[2][128 * BK];   // 16 KB
    const int tid = threadIdx.x;
    const int lane = tid & 63, wid = tid >> 6;
    const int wr = wid >> 1, wc = wid & 1;
    const int hi = lane >> 4, lo = lane & 15;
    const int bm0 = blockIdx.x * 128;
    const int t3 = blockIdx.y >> 3;
    const int bn0 = (blockIdx.y & 7) * 128;
    const float* Bw = (t3 == 0) ? Wqf : (t3 == 1) ? Wkf : Wvf;
    const float* bias = (t3 == 0) ? bq : (t3 == 1) ? bk : bv;

    f32x4 acc[4][4] = {};

    // staging: thread -> rows (srow, srow+64), 8-f32 chunk c4; LDS seg swizzled (proven conflict-free)
    const int srow = tid >> 2;
    const int c4 = tid & 3;
    const int pseg = (c4 ^ ((srow >> 1) & 3)) * 8;   // ushort offset within 32-elem row
    const float* gA0 = X + (size_t)(bm0 + srow) * H_SIZE + c4 * 8;
    const float* gA1 = gA0 + 64 * H_SIZE;
    const float* gB0 = Bw + (size_t)(bn0 + srow) * H_SIZE + c4 * 8;
    const float* gB1 = gB0 + 64 * H_SIZE;

    float4 ra0, ra1, ra2, ra3, rb0, rb1, rb2, rb3;

#define LOADREG(kt)                                        \
    {                                                      \
        ra0 = *(const float4*)(gA0 + (kt));                \
        ra1 = *(const float4*)(gA0 + (kt) + 4);            \
        ra2 = *(const float4*)(gA1 + (kt));                \
        ra3 = *(const float4*)(gA1 + (kt) + 4);            \
        rb0 = *(const float4*)(gB0 + (kt));                \
        rb1 = *(const float4*)(gB0 + (kt) + 4);            \
        rb2 = *(const float4*)(gB1 + (kt));                \
        rb3 = *(const float4*)(gB1 + (kt) + 4);            \
    }
#define CVTWRITE(bb)                                                           \
    {                                                                          \
        uint4 w;                                                               \
        w.x = cvtpk(ra0.x, ra0.y); w.y = cvtpk(ra0.z, ra0.w);                  \
        w.z = cvtpk(ra1.x, ra1.y); w.w = cvtpk(ra1.z, ra1.w);                  \
        *(uint4*)&As[bb][srow * BK + pseg] = w;                                \
        w.x = cvtpk(ra2.x, ra2.y); w.y = cvtpk(ra2.z, ra2.w);                  \
        w.z = cvtpk(ra3.x, ra3.y); w.w = cvtpk(ra3.z, ra3.w);                  \
        *(uint4*)&As[bb][(srow + 64) * BK + pseg] = w;                         \
        w.x = cvtpk(rb0.x, rb0.y); w.y = cvtpk(rb0.z, rb0.w);                  \
        w.z = cvtpk(rb1.x, rb1.y); w.w = cvtpk(rb1.z, rb1.w);                  \
        *(uint4*)&Bs[bb][srow * BK + pseg] = w;                                \
        w.x = cvtpk(rb2.x, rb2.y); w.y = cvtpk(rb2.z, rb2.w);                  \
        w.z = cvtpk(rb3.x, rb3.y); w.w = cvtpk(rb3.z, rb3.w);                  \
        *(uint4*)&Bs[bb][(srow + 64) * BK + pseg] = w;                         \
    }

    LOADREG(0);
    CVTWRITE(0);
    __syncthreads();

    constexpr int NT = H_SIZE / BK;  // 32
    const int rxv = (lo >> 1) & 3;   // read-side swizzle term
    for (int t = 0; t < NT; t++) {
        const int cur = t & 1;
        if (t + 1 < NT) LOADREG((t + 1) * BK);
        {
            bf16_8 af[4], bfv[4];
            const ushort* pa = &As[cur][(wr * 64 + lo) * BK + ((hi ^ rxv) * 8)];
            const ushort* pb = &Bs[cur][(wc * 64 + lo) * BK + ((hi ^ rxv) * 8)];
#pragma unroll
            for (int i = 0; i < 4; i++) af[i] = *(const bf16_8*)(pa + i * 16 * BK);
#pragma unroll
            for (int i = 0; i < 4; i++) bfv[i] = *(const bf16_8*)(pb + i * 16 * BK);
#pragma unroll
            for (int mi = 0; mi < 4; mi++)
#pragma unroll
                for (int ni = 0; ni < 4; ni++)
                    acc[mi][ni] = __builtin_amdgcn_mfma_f32_16x16x32_bf16(
                        af[mi], bfv[ni], acc[mi][ni], 0, 0, 0);
        }
        if (t + 1 < NT) {
            CVTWRITE(cur ^ 1);
            __syncthreads();
        }
    }
#undef LOADREG
#undef CVTWRITE

#pragma unroll
    for (int mi = 0; mi < 4; mi++) {
#pragma unroll
        for (int ni = 0; ni < 4; ni++) {
            const int row0 = bm0 + wr * 64 + mi * 16 + hi * 4;
            const int col = bn0 + wc * 64 + ni * 16 + lo;
            const float bv = bias[col];
            const int h = col >> 6, dk = col & 63;
            if (t3 == 2) {
                const int b = row0 >> 11, l0 = row0 & 2047;
                const int lsw0 = (l0 & ~63) | (((((l0 >> 3) & 7) ^ SWZ(dk)) & 7) << 3) | (l0 & 7);
                uint2 o;
                o.x = cvtpk(acc[mi][ni][0] + bv, acc[mi][ni][1] + bv);
                o.y = cvtpk(acc[mi][ni][2] + bv, acc[mi][ni][3] + bv);
                *(uint2*)&Vtb[((size_t)(b * N_HEADS + h) * D_K + dk) * SEQ + lsw0] = o;
            } else {
#pragma unroll
                for (int rr = 0; rr < 4; rr++) {
                    const int m = row0 + rr;
                    const int b = m >> 11, l = m & 2047;
                    float val = acc[mi][ni][rr] + bv;
                    if (t3 == 0) {
                        Qb[((size_t)(b * N_HEADS + h) * SEQ + l) * D_K + dk] =
                            f2bf(val * 0.18033688f);
                    } else {
                        int dks = ((((dk >> 3) ^ SWZ(l & 63)) & 7) << 3) | (dk & 7);
                        Kb[((size_t)(b * N_HEADS + h) * SEQ + l) * D_K + dks] = f2bf(val);
                    }
                }
            }
        }
    }
}

// ---------------- O-projection GEMM 128x64: A=bf16 Ao (copy), B=fp32 Wo (cvt), 2-buffer ----------------
__global__ __launch_bounds__(256) void gemm_o(const ushort* __restrict__ A,
                                              const float* __restrict__ Wof,
                                              const float* __restrict__ bias,
                                              const float* __restrict__ resid,
                                              float* __restrict__ outp) {
    constexpr int BK = 32;
    __shared__ ushort As[2][128 * BK];  // 16 KB
    __shared__ ushort Bs[2][64 * BK];   // 8 KB
    const int tid = threadIdx.x;
    const int lane = tid & 63, wid = tid >> 6;
    const int wr = wid >> 1, wc = wid & 1;
    const int hi = lane >> 4, lo = lane & 15;
    const int bm0 = blockIdx.x * 128, bn0 = blockIdx.y * 64;

    f32x4 acc[4][2] = {};

    const int srow = tid >> 2;
    const int c4 = tid & 3;
    const int pseg = (c4 ^ ((srow >> 1) & 3)) * 8;
    const ushort* gA0 = A + (size_t)(bm0 + srow) * H_SIZE + c4 * 8;
    const ushort* gA1 = gA0 + 64 * H_SIZE;
    const float* gB0 = Wof + (size_t)(bn0 + srow) * H_SIZE + c4 * 8;   // 64 B-rows

    uint4 wa0, wa1;
    float4 rb0, rb1;

#define LOADREG(kt)                                        \
    {                                                      \
        wa0 = *(const uint4*)(gA0 + (kt));                 \
        wa1 = *(const uint4*)(gA1 + (kt));                 \
        rb0 = *(const float4*)(gB0 + (kt));                \
        rb1 = *(const float4*)(gB0 + (kt) + 4);            \
    }
#define CVTWRITE(bb)                                                           \
    {                                                                          \
        *(uint4*)&As[bb][srow * BK + pseg] = wa0;                              \
        *(uint4*)&As[bb][(srow + 64) * BK + pseg] = wa1;                       \
        uint4 w;                                                               \
        w.x = cvtpk(rb0.x, rb0.y); w.y = cvtpk(rb0.z, rb0.w);                  \
        w.z = cvtpk(rb1.x, rb1.y); w.w = cvtpk(rb1.z, rb1.w);                  \
        *(uint4*)&Bs[bb][srow * BK + pseg] = w;                                \
    }

    LOADREG(0);
    CVTWRITE(0);
    __syncthreads();

    constexpr int NT = H_SIZE / BK;
    const int rxv = (lo >> 1) & 3;
    for (int t = 0; t < NT; t++) {
        const int cur = t & 1;
        if (t + 1 < NT) LOADREG((t + 1) * BK);
        {
            bf16_8 af[4], bfv[2];
            const ushort* pa = &As[cur][(wr * 64 + lo) * BK + ((hi ^ rxv) * 8)];
            const ushort* pb = &Bs[cur][(wc * 32 + lo) * BK + ((hi ^ rxv) * 8)];
#pragma unroll
            for (int i = 0; i < 4; i++) af[i] = *(const bf16_8*)(pa + i * 16 * BK);
#pragma unroll
            for (int i = 0; i < 2; i++) bfv[i] = *(const bf16_8*)(pb + i * 16 * BK);
#pragma unroll
            for (int mi = 0; mi < 4; mi++)
#pragma unroll
                for (int ni = 0; ni < 2; ni++)
                    acc[mi][ni] = __builtin_amdgcn_mfma_f32_16x16x32_bf16(
                        af[mi], bfv[ni], acc[mi][ni], 0, 0, 0);
        }
        if (t + 1 < NT) {
            CVTWRITE(cur ^ 1);
            __syncthreads();
        }
    }
#undef LOADREG
#undef CVTWRITE

#pragma unroll
    for (int mi = 0; mi < 4; mi++) {
#pragma unroll
        for (int ni = 0; ni < 2; ni++) {
            const int row0 = bm0 + wr * 64 + mi * 16 + hi * 4;
            const int col = bn0 + wc * 32 + ni * 16 + lo;
            const float bv = bias[col];
#pragma unroll
            for (int rr = 0; rr < 4; rr++) {
                const int m = row0 + rr;
                outp[(size_t)m * H_SIZE + col] =
                    acc[mi][ni][rr] + bv + resid[(size_t)m * H_SIZE + col];
            }
        }
    }
}

// ---------------- flash attention: z=1, QBLK=32/wave, kh-interleaved, XCD-swizzled (r14) ----------------
__global__ __launch_bounds__(256) void attn_kernel(const ushort* __restrict__ Q,
                                                   const ushort* __restrict__ Ksw,
                                                   const ushort* __restrict__ Vsw,
                                                   ushort* __restrict__ Out) {
    __shared__ ushort Ks[3][64 * 64];   // 24 KB
    __shared__ ushort Vs[3][64 * 64];   // 24 KB
    __shared__ float lsum_lds[4][32];
    const int lane = threadIdx.x & 63, wid = threadIdx.x >> 6;
    const int h32 = lane >> 5, q32 = lane & 31;

    // XCD-aware bijective remap: 512 blocks = 8 XCDs x 64 -> 4 heads per XCD (K/V 2MB L2-fit)
    const int lin = blockIdx.y * gridDim.x + blockIdx.x;
    const int nlin = (lin & 7) * 64 + (lin >> 3);
    const int bx = nlin & 15;
    const int bh = nlin >> 4;            // 0..31
    const int q0 = bx * 128 + wid * 32;
    const ushort* Qh = Q + (size_t)bh * SEQ * D_K;
    const ushort* Kp = Ksw + (size_t)bh * SEQ * D_K;
    const ushort* Vp = Vsw + (size_t)bh * D_K * SEQ;

    bf16_8 qf[4];
#pragma unroll
    for (int tt = 0; tt < 4; tt++)
        qf[tt] = *(const bf16_8*)(Qh + (size_t)(q0 + q32) * D_K + tt * 16 + h32 * 8);

    f32x16 oacc0 = {}, oacc1 = {};
    float ls = 0.f;

    const int koff = wid * 2048 + lane * 16;
    const int vrow = wid * 16 + (lane >> 3);
    const int vseg = (lane & 7) * 16;

#define STAGE(bb, kt)                                                             \
    {                                                                             \
        const char* kg = (const char*)(Kp + (size_t)(kt) * D_K);                  \
        char* kl = (char*)&Ks[bb][0];                                             \
        gld16(kl + koff, kg + koff);                                              \
        gld16(kl + koff + 1024, kg + koff + 1024);                                \
        char* vl = (char*)&Vs[bb][0];                                             \
        gld16(vl + vrow * 128 + vseg,                                             \
              (const char*)(Vp + (size_t)vrow * SEQ + (kt)) + vseg);              \
        gld16(vl + (vrow + 8) * 128 + vseg,                                       \
              (const char*)(Vp + (size_t)(vrow + 8) * SEQ + (kt)) + vseg);        \
    }

    STAGE(0, 0);
    STAGE(1, 64);
    asm volatile("s_waitcnt vmcnt(4)" ::: "memory");
    __builtin_amdgcn_s_barrier();
    __builtin_amdgcn_sched_barrier(0);

    constexpr int NTT = SEQ / 64;  // 32
    int cur = 0;
    for (int t = 0; t < NTT; t++) {
        int c2 = cur + 2; if (c2 >= 3) c2 -= 3;
        if (t + 2 < NTT) STAGE(c2, (t + 2) * 64);
        const ushort* kb = &Ks[cur][0];
        const ushort* vb = &Vs[cur][0];

        f32x16 st0 = {}, st1 = {};
        __builtin_amdgcn_s_setprio(1);
#pragma unroll
        for (int tt = 0; tt < 4; tt++) {
            const int krow = q32;
            int sg = (2 * tt + h32) ^ SWZ(krow);
            bf16_8 kf = *(const bf16_8*)(kb + krow * 64 + sg * 8);
            st0 = __builtin_amdgcn_mfma_f32_32x32x16_bf16(kf, qf[tt], st0, 0, 0, 0);
        }
#pragma unroll
        for (int tt = 0; tt < 4; tt++) {
            const int krow = 32 + q32;
            int sg = (2 * tt + h32) ^ SWZ(krow);
            bf16_8 kf = *(const bf16_8*)(kb + krow * 64 + sg * 8);
            st1 = __builtin_amdgcn_mfma_f32_32x32x16_bf16(kf, qf[tt], st1, 0, 0, 0);
        }
        __builtin_amdgcn_s_setprio(0);

        union { unsigned int w[4]; bf16_8 v; } pf00, pf01;
        float part0 = 0.f;
#pragma unroll
        for (int rr = 0; rr < 16; rr++) { st0[rr] = exp2_raw(st0[rr]); part0 += st0[rr]; }
#pragma unroll
        for (int i = 0; i < 2; i++) {
            unsigned int a = cvtpk(st0[2 * i], st0[2 * i + 1]);
            unsigned int b = cvtpk(st0[4 + 2 * i], st0[4 + 2 * i + 1]);
            asm volatile("v_permlane32_swap_b32 %0, %1" : "+v"(a), "+v"(b));
            pf00.w[i] = a; pf00.w[2 + i] = b;
            unsigned int c = cvtpk(st0[8 + 2 * i], st0[8 + 2 * i + 1]);
            unsigned int d = cvtpk(st0[12 + 2 * i], st0[12 + 2 * i + 1]);
            asm volatile("v_permlane32_swap_b32 %0, %1" : "+v"(c), "+v"(d));
            pf01.w[i] = c; pf01.w[2 + i] = d;
        }
        ls += part0 + __shfl_xor(part0, 32);

        __builtin_amdgcn_s_setprio(1);
        {
            const int vr0 = q32;
            int sg0 = (h32) ^ SWZ(vr0);
            int sg1 = (2 + h32) ^ SWZ(vr0);
            bf16_8 vf0 = *(const bf16_8*)(vb + vr0 * 64 + sg0 * 8);
            bf16_8 vf1 = *(const bf16_8*)(vb + vr0 * 64 + sg1 * 8);
            oacc0 = __builtin_amdgcn_mfma_f32_32x32x16_bf16(pf00.v, vf0, oacc0, 0, 0, 0);
            oacc0 = __builtin_amdgcn_mfma_f32_32x32x16_bf16(pf01.v, vf1, oacc0, 0, 0, 0);
            const int vr1 = 32 + q32;
            int sg2 = (h32) ^ SWZ(vr1);
            int sg3 = (2 + h32) ^ SWZ(vr1);
            bf16_8 vf2 = *(const bf16_8*)(vb + vr1 * 64 + sg2 * 8);
            bf16_8 vf3 = *(const bf16_8*)(vb + vr1 * 64 + sg3 * 8);
            oacc1 = __builtin_amdgcn_mfma_f32_32x32x16_bf16(pf00.v, vf2, oacc1, 0, 0, 0);
            oacc1 = __builtin_amdgcn_mfma_f32_32x32x16_bf16(pf01.v, vf3, oacc1, 0, 0, 0);
        }
        __builtin_amdgcn_s_setprio(0);

        union { unsigned int w[4]; bf16_8 v; } pf10, pf11;
        float part1 = 0.f;
#pragma unroll
        for (int rr = 0; rr < 16; rr++) { st1[rr] = exp2_raw(st1[rr]); part1 += st1[rr]; }
#pragma unroll
        for (int i = 0; i < 2; i++) {
            unsigned int a = cvtpk(st1[2 * i], st1[2 * i + 1]);
            unsigned int b = cvtpk(st1[4 + 2 * i], st1[4 + 2 * i + 1]);
            asm volatile("v_permlane32_swap_b32 %0, %1" : "+v"(a), "+v"(b));
            pf10.w[i] = a; pf10.w[2 + i] = b;
            unsigned int c = cvtpk(st1[8 + 2 * i], st1[8 + 2 * i + 1]);
            unsigned int d = cvtpk(st1[12 + 2 * i], st1[12 + 2 * i + 1]);
            asm volatile("v_permlane32_swap_b32 %0, %1" : "+v"(c), "+v"(d));
            pf11.w[i] = c; pf11.w[2 + i] = d;
        }
        ls += part1 + __shfl_xor(part1, 32);

        __builtin_amdgcn_s_setprio(1);
        {
            const int vr0 = q32;
            int sg0 = (4 + h32) ^ SWZ(vr0);
            int sg1 = (6 + h32) ^ SWZ(vr0);
            bf16_8 vf0 = *(const bf16_8*)(vb + vr0 * 64 + sg0 * 8);
            bf16_8 vf1 = *(const bf16_8*)(vb + vr0 * 64 + sg1 * 8);
            oacc0 = __builtin_amdgcn_mfma_f32_32x32x16_bf16(pf10.v, vf0, oacc0, 0, 0, 0);
            oacc0 = __builtin_amdgcn_mfma_f32_32x32x16_bf16(pf11.v, vf1, oacc0, 0, 0, 0);
            const int vr1 = 32 + q32;
            int sg2 = (4 + h32) ^ SWZ(vr1);
            int sg3 = (6 + h32) ^ SWZ(vr1);
            bf16_8 vf2 = *(const bf16_8*)(vb + vr1 * 64 + sg2 * 8);
            bf16_8 vf3 = *(const bf16_8*)(vb + vr1 * 64 + sg3 * 8);
            oacc1 = __builtin_amdgcn_mfma_f32_32x32x16_bf16(pf10.v, vf2, oacc1, 0, 0, 0);
            oacc1 = __builtin_amdgcn_mfma_f32_32x32x16_bf16(pf11.v, vf3, oacc1, 0, 0, 0);
        }
        __builtin_amdgcn_s_setprio(0);

        if (t + 1 < NTT) {
            if (t + 2 < NTT) { asm volatile("s_waitcnt vmcnt(4)" ::: "memory"); }
            else             { asm volatile("s_waitcnt vmcnt(0)" ::: "memory"); }
            __builtin_amdgcn_s_barrier();
            __builtin_amdgcn_sched_barrier(0);
        }
        cur = cur + 1; if (cur >= 3) cur -= 3;
    }
#undef STAGE

    if (lane < 32) lsum_lds[wid][q32] = 1.0f / ls;
    const int b = bh >> 4, h = bh & 15;
#pragma unroll
    for (int rr = 0; rr < 16; rr++) {
        const int qloc = (rr & 3) + 8 * (rr >> 2) + 4 * h32;
        const float inv = lsum_lds[wid][qloc];
        const int l = q0 + qloc;
        ushort* orow = Out + ((size_t)(b * SEQ + l)) * H_SIZE + h * 64;
        orow[q32] = f2bf(oacc0[rr] * inv);
        orow[32 + q32] = f2bf(oacc1[rr] * inv);
    }
}

// ---------------- LayerNorm in-place on d_out ----------------
__global__ __launch_bounds__(256) void ln_kernel(float* __restrict__ y,
                                                 const float* __restrict__ gamma,
                                                 const float* __restrict__ beta) {
    const int row = blockIdx.x;
    float4* p = (float4*)(y + (size_t)row * H_SIZE);
    float4 v = p[threadIdx.x];
    float s = v.x + v.y + v.z + v.w;
    float s2 = v.x * v.x + v.y * v.y + v.z * v.z + v.w * v.w;
#pragma unroll
    for (int off = 1; off < 64; off <<= 1) {
        s += __shfl_xor(s, off);
        s2 += __shfl_xor(s2, off);
    }
    __shared__ float ss[4], ss2[4];
    const int wid = threadIdx.x >> 6, lane = threadIdx.x & 63;
    if (lane == 0) { ss[wid] = s; ss2[wid] = s2; }
    __syncthreads();
    s = ss[0] + ss[1] + ss[2] + ss[3];
    s2 = ss2[0] + ss2[1] + ss2[2] + ss2[3];
    const float mean = s * (1.0f / H_SIZE);
    const float var = s2 * (1.0f / H_SIZE) - mean * mean;
    const float rstd = rsqrtf(var + 1e-5f);
    const float4 g = ((const float4*)gamma)[threadIdx.x];
    const float4 bt = ((const float4*)beta)[threadIdx.x];
    float4 o;
    o.x = (v.x - mean) * rstd * g.x + bt.x;
    o.y = (v.y - mean) * rstd * g.y + bt.y;
    o.z = (v.z - mean) * rstd * g.z + bt.z;
    o.w = (v.w - mean) * rstd * g.w + bt.w;
    p[threadIdx.x] = o;
}

extern "C" void kernel_launch(void* const* d_in, const int* in_sizes, int n_in,
                              void* d_out, int out_size, void* d_ws, size_t ws_size,
                              hipStream_t stream) {
    const float* x = (const float*)d_in[0];
    const float* Wq = (const float*)d_in[1];
    const float* bq = (const float*)d_in[2];
    const float* Wk = (const float*)d_in[3];
    const float* bk = (const float*)d_in[4];
    const float* Wv = (const float*)d_in[5];
    const float* bv = (const float*)d_in[6];
    const float* Wo = (const float*)d_in[7];
    const float* bo = (const float*)d_in[8];
    const float* gamma = (const float*)d_in[9];
    const float* beta = (const float*)d_in[10];

    char* ws = (char*)d_ws;
    ushort* Qb  = (ushort*)(ws + (16u << 20));      // 8 MB [b,h,l,dk] (x 0.125*log2e)
    ushort* Kb  = (ushort*)(ws + (24u << 20));      // 8 MB [b,h,l,dk] SWZ-swizzled
    ushort* Vtb = (ushort*)(ws + (32u << 20));      // 8 MB [b,h,dk,l] SWZ-swizzled
    ushort* Ao  = (ushort*)(ws + (40u << 20));      // 8 MB attn out bf16 [m,H]

    dim3 gq(M_TOT / 128, 24);
    gemm_qkv<<<gq, 256, 0, stream>>>(x, Wq, Wk, Wv, bq, bk, bv, Qb, Kb, Vtb);

    dim3 g2(SEQ / 128, BATCH * N_HEADS);
    attn_kernel<<<g2, 256, 0, stream>>>(Qb, Kb, Vtb, Ao);

    dim3 go(M_TOT / 128, H_SIZE / 64);
    gemm_o<<<go, 256, 0, stream>>>(Ao, Wo, bo, x, (float*)d_out);

    ln_kernel<<<M_TOT, 256, 0, stream>>>((float*)d_out, gamma, beta);
}